// Round 3
// baseline (136.963 us; speedup 1.0000x reference)
//
#include <hip/hip_runtime.h>

#define BATCH 64
#define GRIDW 38
#define HW 1444            // 38*38
#define NBOX 16
#define NANC 5
#define NCLS 20
#define SLOTS 7220         // HW * NANC
#define CIN 125            // (21+4)*5
#define EPSC 0.0009765625f // 2^-10
#define PSTRIDE 8          // s_pos, s_neg, s_cls, s_txty, s_twth, inv_pos, inv_neg, npos
#define MAGIC 0x5EEDFACEu

struct BoxRec {
  int   cell;   // row*38+col
  int   ids;    // best anchor
  int   lab;    // glabel-1 in [0,20)
  float tx, ty, tw, th;
  float wleft;  // gboxes_ltrb[...,0] — the reference's "w_pos" (index 26 bug)
};

__constant__ float ANCW[5] = {0.05f, 0.12f, 0.25f, 0.45f, 0.75f};
__constant__ float ANCH[5] = {0.07f, 0.15f, 0.30f, 0.55f, 0.80f};

// Single fused kernel: one block per batch item (64 blocks).
//  - box matching recomputed in-block (16 threads, trivial)
//  - per-batch pos/ignore counts are block-local (no cross-block count reduce)
//  - completion protocol: each block release-stores MAGIC flag after writing
//    its 8 partials; block 63 acquire-spins on all 64 flags, then reduces
//    64x8 floats in double and writes the scalar. Robust to any d_ws init
//    (0xAA poison != MAGIC); 64 blocks << 256 CUs so all are co-resident.
__global__ void __launch_bounds__(256) fused_kernel(
    const float* __restrict__ pyolos,
    const float* __restrict__ gboxes,
    const int* __restrict__ glabels,
    float* __restrict__ partials,        // [BATCH][PSTRIDE]
    unsigned int* __restrict__ flags,    // [BATCH]
    float* __restrict__ out) {
  int b = blockIdx.x;

  __shared__ BoxRec sbox[NBOX];
  if (threadIdx.x < NBOX) {
    int n = threadIdx.x;
    const float* gb = gboxes + ((size_t)b * NBOX + n) * 4;
    float l  = gb[0], t = gb[1], r = gb[2], bt = gb[3];
    float cx = (l + r) * 0.5f, cy = (t + bt) * 0.5f;
    float w  = r - l,          h  = bt - t;
    int best = 0; float bestv = -1.0f;
    #pragma unroll
    for (int a = 0; a < NANC; ++a) {
      float inter = fminf(w, ANCW[a]) * fminf(h, ANCH[a]);
      float uni   = w * h + ANCW[a] * ANCH[a] - inter;
      float iou   = inter / uni;
      if (iou > bestv) { bestv = iou; best = a; }  // strict >: first-max (jnp.argmax)
    }
    int col = (int)floorf(cx * (float)GRIDW);
    int row = (int)floorf(cy * (float)GRIDW);
    col = min(max(col, 0), GRIDW - 1);
    row = min(max(row, 0), GRIDW - 1);
    BoxRec rec;
    rec.cell  = row * GRIDW + col;
    rec.ids   = best;
    rec.lab   = glabels[(size_t)b * NBOX + n] - 1;
    rec.tx    = cx * (float)GRIDW - (float)col;
    rec.ty    = cy * (float)GRIDW - (float)row;
    rec.tw    = logf(w / ANCW[best]);
    rec.th    = logf(h / ANCH[best]);
    rec.wleft = l;   // replicate gy[...,26] usage (reference reads gboxes[...,0] here)
    sbox[n] = rec;
  }
  __syncthreads();

  float s_pos = 0.f, s_neg = 0.f, s_cls = 0.f, s_txty = 0.f, s_twth = 0.f;
  float c_pos = 0.f, c_ign = 0.f;

  const float* pbase = pyolos + (size_t)b * CIN * HW;
  for (int sIdx = threadIdx.x; sIdx < SLOTS; sIdx += 256) {
    int j = sIdx / HW;          // anchor, 0..4
    int k = sIdx - j * HW;      // grid cell, 0..1443  (k fastest -> coalesced)

    // Replicate scatter semantics: all -1 marks first, then tvec in box order
    // (last box wins on (cell,anchor) duplicates).
    int posbox = -1; bool cellmatch = false;
    #pragma unroll
    for (int n = 0; n < NBOX; ++n) {
      if (sbox[n].cell == k) {
        cellmatch = true;
        if (sbox[n].ids == j) posbox = n;
      }
    }

    const float* pb = pbase + k;   // channel i, anchor j -> pb[(i*5+j)*HW]
    float pconf = 1.0f / (1.0f + expf(-pb[(size_t)j * HW]));
    pconf = fminf(fmaxf(pconf, EPSC), 1.0f - EPSC);

    if (posbox >= 0) {
      c_pos += 1.f;
      float om = 1.0f - pconf;
      s_pos += -0.5f * om * om * logf(pconf);    // gconf=1, mpf=1
      BoxRec rec = sbox[posbox];
      // class BCE over 20 classes, target one-hot(lab)
      float csum = 0.f;
      for (int c = 0; c < NCLS; ++c) {
        float pc = 1.0f / (1.0f + expf(-pb[(size_t)((1 + c) * NANC + j) * HW]));
        pc = fminf(fmaxf(pc, EPSC), 1.0f - EPSC);
        csum += (c == rec.lab) ? -logf(pc) : -logf(1.0f - pc);
      }
      s_cls += csum;
      // txty BCE * wleft
      float px = 1.0f / (1.0f + expf(-pb[(size_t)(21 * NANC + j) * HW]));
      float py = 1.0f / (1.0f + expf(-pb[(size_t)(22 * NANC + j) * HW]));
      px = fminf(fmaxf(px, EPSC), 1.0f - EPSC);
      py = fminf(fmaxf(py, EPSC), 1.0f - EPSC);
      float bx = -(rec.tx * logf(px) + (1.0f - rec.tx) * logf(1.0f - px));
      float by = -(rec.ty * logf(py) + (1.0f - rec.ty) * logf(1.0f - py));
      s_txty += (bx + by) * rec.wleft;
      // twth L2 * wleft
      float pw = pb[(size_t)(23 * NANC + j) * HW];
      float ph = pb[(size_t)(24 * NANC + j) * HW];
      float dw = pw - rec.tw, dh = ph - rec.th;
      s_twth += (dw * dw + dh * dh) * rec.wleft;
    } else if (cellmatch) {
      c_ign += 1.f;   // gconf = -1: contributes to neither pos nor neg
    } else {
      s_neg += -0.5f * pconf * pconf * logf(1.0f - pconf);
    }
  }

  // block reduction: wave shfl (width 64) then cross-wave via LDS
  __shared__ float red[4][7];
  int lane = threadIdx.x & 63;
  int wid  = threadIdx.x >> 6;
  for (int off = 32; off; off >>= 1) {
    s_pos  += __shfl_down(s_pos,  off, 64);
    s_neg  += __shfl_down(s_neg,  off, 64);
    s_cls  += __shfl_down(s_cls,  off, 64);
    s_txty += __shfl_down(s_txty, off, 64);
    s_twth += __shfl_down(s_twth, off, 64);
    c_pos  += __shfl_down(c_pos,  off, 64);
    c_ign  += __shfl_down(c_ign,  off, 64);
  }
  if (lane == 0) {
    red[wid][0] = s_pos;  red[wid][1] = s_neg; red[wid][2] = s_cls;
    red[wid][3] = s_txty; red[wid][4] = s_twth;
    red[wid][5] = c_pos;  red[wid][6] = c_ign;
  }
  __syncthreads();

  if (threadIdx.x == 0) {
    float a[7] = {0, 0, 0, 0, 0, 0, 0};
    for (int w2 = 0; w2 < 4; ++w2)
      for (int q = 0; q < 7; ++q) a[q] += red[w2][q];
    float npos = a[5];
    float nneg = (float)SLOTS - a[5] - a[6];
    float* mine = partials + (size_t)b * PSTRIDE;
    mine[0] = a[0];                       // s_pos
    mine[1] = a[1];                       // s_neg
    mine[2] = a[2];                       // s_cls
    mine[3] = a[3];                       // s_txty
    mine[4] = a[4];                       // s_twth
    mine[5] = 1.0f / fmaxf(npos, EPSC);   // inv_pos_b
    mine[6] = 1.0f / fmaxf(nneg, EPSC);   // inv_neg_b
    mine[7] = npos;
    __threadfence();
    __hip_atomic_store(&flags[b], MAGIC, __ATOMIC_RELEASE, __HIP_MEMORY_SCOPE_AGENT);

    // last block finalizes
    if (b == BATCH - 1) {
      for (int i = 0; i < BATCH; ++i) {
        while (__hip_atomic_load(&flags[i], __ATOMIC_ACQUIRE,
                                 __HIP_MEMORY_SCOPE_AGENT) != MAGIC) {
          __builtin_amdgcn_s_sleep(1);
        }
      }
      __threadfence();
      double spos = 0, sneg = 0, scls = 0, stxty = 0, stwth = 0;
      double sinvp = 0, sinvn = 0, snpos = 0;
      for (int i = 0; i < BATCH; ++i) {
        const float* p = partials + (size_t)i * PSTRIDE;
        spos  += (double)__hip_atomic_load(&p[0], __ATOMIC_RELAXED, __HIP_MEMORY_SCOPE_AGENT);
        sneg  += (double)__hip_atomic_load(&p[1], __ATOMIC_RELAXED, __HIP_MEMORY_SCOPE_AGENT);
        scls  += (double)__hip_atomic_load(&p[2], __ATOMIC_RELAXED, __HIP_MEMORY_SCOPE_AGENT);
        stxty += (double)__hip_atomic_load(&p[3], __ATOMIC_RELAXED, __HIP_MEMORY_SCOPE_AGENT);
        stwth += (double)__hip_atomic_load(&p[4], __ATOMIC_RELAXED, __HIP_MEMORY_SCOPE_AGENT);
        sinvp += (double)__hip_atomic_load(&p[5], __ATOMIC_RELAXED, __HIP_MEMORY_SCOPE_AGENT);
        sinvn += (double)__hip_atomic_load(&p[6], __ATOMIC_RELAXED, __HIP_MEMORY_SCOPE_AGENT);
        snpos += (double)__hip_atomic_load(&p[7], __ATOMIC_RELAXED, __HIP_MEMORY_SCOPE_AGENT);
      }
      double n_pos_tot = fmax(snpos, 1.0);
      double loss = spos * (sinvp / (double)BATCH)          // l_conf_pos
                  + 3.0 * sneg * (sinvn / (double)BATCH)    // l_conf_neg
                  + scls  / n_pos_tot                       // l_cls
                  + stxty / n_pos_tot                       // l_txty
                  + stwth / n_pos_tot;                      // l_twth
      out[0] = (float)loss;
    }
  }
}

extern "C" void kernel_launch(void* const* d_in, const int* in_sizes, int n_in,
                              void* d_out, int out_size, void* d_ws, size_t ws_size,
                              hipStream_t stream) {
  const float* pyolos  = (const float*)d_in[0];
  const float* gboxes  = (const float*)d_in[1];
  const int*   glabels = (const int*)d_in[2];
  float* out = (float*)d_out;

  // ws layout:
  //   [0,    2048)  float partials[64][8]
  //   [2048, 2304)  unsigned flags[64]   (any init value != MAGIC is fine; the
  //                 harness's 0xAA poison or zeros both satisfy that)
  float*        partials = (float*)d_ws;
  unsigned int* flags    = (unsigned int*)((char*)d_ws + 2048);

  fused_kernel<<<BATCH, 256, 0, stream>>>(pyolos, gboxes, glabels,
                                          partials, flags, out);
}

// Round 4
// 127.760 us; speedup vs baseline: 1.0720x; 1.0720x over previous
//
#include <hip/hip_runtime.h>

#define BATCH 64
#define GRIDW 38
#define HW 1444            // 38*38
#define NBOX 16
#define NANC 5
#define NCLS 20
#define SLOTS 7220         // HW * NANC
#define CIN 125            // (21+4)*5
#define EPSC 0.0009765625f // 2^-10
#define PSTRIDE 8          // s_pos, s_neg, s_cls, s_txty, s_twth, inv_pos, inv_neg, npos
#define MAGIC 0x5EEDFACEu

struct BoxRec {
  int   cell;   // row*38+col
  int   ids;    // best anchor
  int   lab;    // glabel-1 in [0,20)
  float tx, ty, tw, th;
  float wleft;  // gboxes_ltrb[...,0] — the reference's "w_pos" (index 26 bug)
};

__constant__ float ANCW[5] = {0.05f, 0.12f, 0.25f, 0.45f, 0.75f};
__constant__ float ANCH[5] = {0.07f, 0.15f, 0.30f, 0.55f, 0.80f};

// Single fused kernel, one block per batch item (64 blocks, all co-resident).
// R3 lesson: the finalize MUST be parallel — a serial 512x agent-scope atomic
// load chain cost ~65 us. Here lane i of wave 0 (block 63) spins on flags[i]
// in parallel, loads partials[i][0..7] in parallel, and the block reduces via
// 64-lane shuffles. Serial dependent L3 round-trips: ~512 -> ~8.
__global__ void __launch_bounds__(256) fused_kernel(
    const float* __restrict__ pyolos,
    const float* __restrict__ gboxes,
    const int* __restrict__ glabels,
    float* __restrict__ partials,        // [BATCH][PSTRIDE]
    unsigned int* __restrict__ flags,    // [BATCH]
    float* __restrict__ out) {
  int b = blockIdx.x;

  __shared__ BoxRec sbox[NBOX];
  if (threadIdx.x < NBOX) {
    int n = threadIdx.x;
    const float* gb = gboxes + ((size_t)b * NBOX + n) * 4;
    float l  = gb[0], t = gb[1], r = gb[2], bt = gb[3];
    float cx = (l + r) * 0.5f, cy = (t + bt) * 0.5f;
    float w  = r - l,          h  = bt - t;
    int best = 0; float bestv = -1.0f;
    #pragma unroll
    for (int a = 0; a < NANC; ++a) {
      float inter = fminf(w, ANCW[a]) * fminf(h, ANCH[a]);
      float uni   = w * h + ANCW[a] * ANCH[a] - inter;
      float iou   = inter / uni;
      if (iou > bestv) { bestv = iou; best = a; }  // strict >: first-max (jnp.argmax)
    }
    int col = (int)floorf(cx * (float)GRIDW);
    int row = (int)floorf(cy * (float)GRIDW);
    col = min(max(col, 0), GRIDW - 1);
    row = min(max(row, 0), GRIDW - 1);
    BoxRec rec;
    rec.cell  = row * GRIDW + col;
    rec.ids   = best;
    rec.lab   = glabels[(size_t)b * NBOX + n] - 1;
    rec.tx    = cx * (float)GRIDW - (float)col;
    rec.ty    = cy * (float)GRIDW - (float)row;
    rec.tw    = logf(w / ANCW[best]);
    rec.th    = logf(h / ANCH[best]);
    rec.wleft = l;   // replicate gy[...,26] usage (reference reads gboxes[...,0] here)
    sbox[n] = rec;
  }
  __syncthreads();

  float s_pos = 0.f, s_neg = 0.f, s_cls = 0.f, s_txty = 0.f, s_twth = 0.f;
  float c_pos = 0.f, c_ign = 0.f;

  const float* pbase = pyolos + (size_t)b * CIN * HW;
  for (int sIdx = threadIdx.x; sIdx < SLOTS; sIdx += 256) {
    int j = sIdx / HW;          // anchor, 0..4
    int k = sIdx - j * HW;      // grid cell, 0..1443  (k fastest -> coalesced)

    // Replicate scatter semantics: all -1 marks first, then tvec in box order
    // (last box wins on (cell,anchor) duplicates).
    int posbox = -1; bool cellmatch = false;
    #pragma unroll
    for (int n = 0; n < NBOX; ++n) {
      if (sbox[n].cell == k) {
        cellmatch = true;
        if (sbox[n].ids == j) posbox = n;
      }
    }

    const float* pb = pbase + k;   // channel i, anchor j -> pb[(i*5+j)*HW]
    float pconf = 1.0f / (1.0f + expf(-pb[(size_t)j * HW]));
    pconf = fminf(fmaxf(pconf, EPSC), 1.0f - EPSC);

    if (posbox >= 0) {
      c_pos += 1.f;
      float om = 1.0f - pconf;
      s_pos += -0.5f * om * om * logf(pconf);    // gconf=1, mpf=1
      BoxRec rec = sbox[posbox];
      // class BCE over 20 classes, target one-hot(lab)
      float csum = 0.f;
      for (int c = 0; c < NCLS; ++c) {
        float pc = 1.0f / (1.0f + expf(-pb[(size_t)((1 + c) * NANC + j) * HW]));
        pc = fminf(fmaxf(pc, EPSC), 1.0f - EPSC);
        csum += (c == rec.lab) ? -logf(pc) : -logf(1.0f - pc);
      }
      s_cls += csum;
      // txty BCE * wleft
      float px = 1.0f / (1.0f + expf(-pb[(size_t)(21 * NANC + j) * HW]));
      float py = 1.0f / (1.0f + expf(-pb[(size_t)(22 * NANC + j) * HW]));
      px = fminf(fmaxf(px, EPSC), 1.0f - EPSC);
      py = fminf(fmaxf(py, EPSC), 1.0f - EPSC);
      float bx = -(rec.tx * logf(px) + (1.0f - rec.tx) * logf(1.0f - px));
      float by = -(rec.ty * logf(py) + (1.0f - rec.ty) * logf(1.0f - py));
      s_txty += (bx + by) * rec.wleft;
      // twth L2 * wleft
      float pw = pb[(size_t)(23 * NANC + j) * HW];
      float ph = pb[(size_t)(24 * NANC + j) * HW];
      float dw = pw - rec.tw, dh = dh = ph - rec.th;
      s_twth += (dw * dw + dh * dh) * rec.wleft;
    } else if (cellmatch) {
      c_ign += 1.f;   // gconf = -1: contributes to neither pos nor neg
    } else {
      s_neg += -0.5f * pconf * pconf * logf(1.0f - pconf);
    }
  }

  // block reduction: wave shfl (width 64) then cross-wave via LDS
  __shared__ float red[4][7];
  int lane = threadIdx.x & 63;
  int wid  = threadIdx.x >> 6;
  for (int off = 32; off; off >>= 1) {
    s_pos  += __shfl_down(s_pos,  off, 64);
    s_neg  += __shfl_down(s_neg,  off, 64);
    s_cls  += __shfl_down(s_cls,  off, 64);
    s_txty += __shfl_down(s_txty, off, 64);
    s_twth += __shfl_down(s_twth, off, 64);
    c_pos  += __shfl_down(c_pos,  off, 64);
    c_ign  += __shfl_down(c_ign,  off, 64);
  }
  if (lane == 0) {
    red[wid][0] = s_pos;  red[wid][1] = s_neg; red[wid][2] = s_cls;
    red[wid][3] = s_txty; red[wid][4] = s_twth;
    red[wid][5] = c_pos;  red[wid][6] = c_ign;
  }
  __syncthreads();

  if (threadIdx.x == 0) {
    float a[7] = {0, 0, 0, 0, 0, 0, 0};
    for (int w2 = 0; w2 < 4; ++w2)
      for (int q = 0; q < 7; ++q) a[q] += red[w2][q];
    float npos = a[5];
    float nneg = (float)SLOTS - a[5] - a[6];
    float* mine = partials + (size_t)b * PSTRIDE;
    mine[0] = a[0];                       // s_pos
    mine[1] = a[1];                       // s_neg
    mine[2] = a[2];                       // s_cls
    mine[3] = a[3];                       // s_txty
    mine[4] = a[4];                       // s_twth
    mine[5] = 1.0f / fmaxf(npos, EPSC);   // inv_pos_b
    mine[6] = 1.0f / fmaxf(nneg, EPSC);   // inv_neg_b
    mine[7] = npos;
    __threadfence();
    __hip_atomic_store(&flags[b], MAGIC, __ATOMIC_RELEASE, __HIP_MEMORY_SCOPE_AGENT);
  }

  // ---- parallel finalize: wave 0 of the last block ----
  if (b == BATCH - 1 && threadIdx.x < BATCH) {
    int i = threadIdx.x;   // lane i owns batch i (parallel spin + parallel loads)
    unsigned f;
    do {
      f = __hip_atomic_load(&flags[i], __ATOMIC_ACQUIRE, __HIP_MEMORY_SCOPE_AGENT);
      if (f != MAGIC) __builtin_amdgcn_s_sleep(1);
    } while (f != MAGIC);

    // agent-scope relaxed atomic loads: read from coherence point (L3), immune
    // to stale per-XCD L2 lines from a previous graph-replay iteration.
    const float* p = partials + (size_t)i * PSTRIDE;
    double v[PSTRIDE];
    #pragma unroll
    for (int q = 0; q < PSTRIDE; ++q)
      v[q] = (double)__hip_atomic_load(&p[q], __ATOMIC_RELAXED, __HIP_MEMORY_SCOPE_AGENT);

    #pragma unroll
    for (int off = 32; off; off >>= 1)
      #pragma unroll
      for (int q = 0; q < PSTRIDE; ++q)
        v[q] += __shfl_down(v[q], off, 64);

    if (i == 0) {
      double n_pos_tot = fmax(v[7], 1.0);
      double loss = v[0] * (v[5] / (double)BATCH)          // l_conf_pos
                  + 3.0 * v[1] * (v[6] / (double)BATCH)    // l_conf_neg
                  + v[2] / n_pos_tot                       // l_cls
                  + v[3] / n_pos_tot                       // l_txty
                  + v[4] / n_pos_tot;                      // l_twth
      out[0] = (float)loss;
    }
  }
}

extern "C" void kernel_launch(void* const* d_in, const int* in_sizes, int n_in,
                              void* d_out, int out_size, void* d_ws, size_t ws_size,
                              hipStream_t stream) {
  const float* pyolos  = (const float*)d_in[0];
  const float* gboxes  = (const float*)d_in[1];
  const int*   glabels = (const int*)d_in[2];
  float* out = (float*)d_out;

  // ws layout:
  //   [0,    2048)  float partials[64][8]
  //   [2048, 2304)  unsigned flags[64]  (0xAA poison != MAGIC, so no memset needed)
  float*        partials = (float*)d_ws;
  unsigned int* flags    = (unsigned int*)((char*)d_ws + 2048);

  fused_kernel<<<BATCH, 256, 0, stream>>>(pyolos, gboxes, glabels,
                                          partials, flags, out);
}